// Round 2
// baseline (585.224 us; speedup 1.0000x reference)
//
#include <hip/hip_runtime.h>

#define D_ 32
#define HID_ 128
#define ROWS 16

__device__ __forceinline__ float sigmoidf_(float x) {
    return 1.0f / (1.0f + expf(-x));
}

// ---------- mean reduction, stage 1 (deterministic, no atomics) ----------
__global__ __launch_bounds__(256) void k_mean1(
    const float* __restrict__ X_obs, const float* __restrict__ M_obs,
    float* __restrict__ partials, int n_obs, int chunk)
{
    int d = threadIdx.x & 31;
    int sub = threadIdx.x >> 5;          // 0..7
    int start = blockIdx.x * chunk;
    int end = start + chunk;
    if (end > n_obs) end = n_obs;
    float sx = 0.f, sm = 0.f;
    for (int j = start + sub; j < end; j += 8) {
        sx += X_obs[j * D_ + d];
        sm += M_obs[j * D_ + d] + 1e-6f;
    }
    __shared__ float redx[8][33];
    __shared__ float redm[8][33];
    redx[sub][d] = sx;
    redm[sub][d] = sm;
    __syncthreads();
    if (sub == 0) {
        float tx = 0.f, tm = 0.f;
        #pragma unroll
        for (int s = 0; s < 8; s++) { tx += redx[s][d]; tm += redm[s][d]; }
        partials[blockIdx.x * 64 + d] = tx;
        partials[blockIdx.x * 64 + 32 + d] = tm;
    }
}

// ---------- mean reduction, stage 2 ----------
__global__ void k_mean2(const float* __restrict__ partials, float* __restrict__ mean_x, int nblk)
{
    int d = threadIdx.x;
    if (d < 32) {
        float sx = 0.f, sm = 0.f;
        for (int b = 0; b < nblk; b++) {
            sx += partials[b * 64 + d];
            sm += partials[b * 64 + 32 + d];
        }
        mean_x[d] = sx / sm;
    }
}

// ---------- copy-through of all rows (observed rows overwritten later) ----------
__global__ __launch_bounds__(256) void k_copy(
    const float4* __restrict__ mgn_h, const float4* __restrict__ last_x, const float4* __restrict__ last_t,
    float4* __restrict__ out_h, float4* __restrict__ out_lx, float4* __restrict__ out_lt,
    int n)
{
    long nh = (long)n * (HID_ / 4);      // float4 count of mgn_h
    long nx = (long)n * (D_ / 4);        // float4 count of last_x / last_t
    long total = nh + 2 * nx;
    for (long i = blockIdx.x * (long)blockDim.x + threadIdx.x; i < total;
         i += (long)gridDim.x * blockDim.x) {
        if (i < nh)            out_h[i] = mgn_h[i];
        else if (i < nh + nx)  out_lx[i - nh] = last_x[i - nh];
        else                   out_lt[i - nh - nx] = last_t[i - nh - nx];
    }
}

// ---------- fused GRU-D main kernel: 16 rows per 256-thread block ----------
__global__ __launch_bounds__(256) void k_main(
    const float* __restrict__ ct_p,
    const float* __restrict__ mgn_h,
    const float* __restrict__ X_obs,
    const float* __restrict__ M_obs,
    const int*   __restrict__ i_obs,
    const float* __restrict__ last_x,
    const float* __restrict__ last_t,
    const float* __restrict__ W_gx,
    const float* __restrict__ W_gh,
    const float* __restrict__ Wz, const float* __restrict__ Vz, const float* __restrict__ Uz, const float* __restrict__ bz,
    const float* __restrict__ Wr, const float* __restrict__ Vr, const float* __restrict__ Ur, const float* __restrict__ br,
    const float* __restrict__ Wh, const float* __restrict__ Vh, const float* __restrict__ Uh, const float* __restrict__ bh,
    const float* __restrict__ mean_x,
    float* __restrict__ out_h, float* __restrict__ out_lx, float* __restrict__ out_lt,
    int n_obs)
{
    __shared__ __attribute__((aligned(16))) float s_intv[ROWS][D_];
    __shared__ __attribute__((aligned(16))) float s_M[ROWS][D_];
    __shared__ __attribute__((aligned(16))) float s_X[ROWS][D_];
    __shared__ __attribute__((aligned(16))) float s_lxn[ROWS][D_];
    __shared__ __attribute__((aligned(16))) float s_xhat[ROWS][D_];
    __shared__ __attribute__((aligned(16))) float s_h[ROWS][HID_];
    __shared__ __attribute__((aligned(16))) float s_rh[ROWS][HID_];
    __shared__ int   s_idx[ROWS];
    __shared__ float s_mean[D_];

    int t = threadIdx.x;
    int row0 = blockIdx.x * ROWS;
    if (t < ROWS) {
        int j = row0 + t;
        s_idx[t] = (j < n_obs) ? i_obs[j] : -1;
    }
    if (t >= 32 && t < 64) s_mean[t - 32] = mean_x[t - 32];
    __syncthreads();
    float ctv = ct_p[0];

    // ---- phase 1: pointwise updates of last_x / last_t, stash interval etc. ----
    for (int u = t; u < ROWS * D_; u += 256) {
        int rr = u >> 5, d = u & 31;
        int gi = s_idx[rr];
        float itv = 0.f, Mm = 0.f, Xv = 0.f, lxn = 0.f;
        if (gi >= 0) {
            int j = row0 + rr;
            Xv = X_obs[j * D_ + d];
            Mm = M_obs[j * D_ + d];
            float lx = last_x[(long)gi * D_ + d];
            float lt = last_t[(long)gi * D_ + d];
            itv = ctv - lt;
            lxn = lx * (1.f - Mm) + Xv * Mm;
            float ltn = lt * (1.f - Mm) + ctv * Mm;
            out_lx[(long)gi * D_ + d] = lxn;
            out_lt[(long)gi * D_ + d] = ltn;
        }
        s_intv[rr][d] = itv;
        s_M[rr][d]    = Mm;
        s_X[rr][d]    = Xv;
        s_lxn[rr][d]  = lxn;
    }
    __syncthreads();

    // ---- phase 2: gamma_x -> X_hat ----
    for (int u = t; u < ROWS * D_; u += 256) {
        int rr = u >> 5, d = u & 31;
        const float4* wp = (const float4*)(W_gx + d * D_);
        const float4* ip = (const float4*)(&s_intv[rr][0]);
        float s = 0.f;
        #pragma unroll
        for (int k4 = 0; k4 < 8; k4++) {
            float4 w = wp[k4], v = ip[k4];
            s += v.x * w.x + v.y * w.y + v.z * w.z + v.w * w.w;
        }
        float gx = expf(-fmaxf(s, 0.f));
        float Mm = s_M[rr][d];
        float xh = Mm * s_X[rr][d]
                 + (1.f - Mm) * (gx * s_lxn[rr][d] + (1.f - gx) * s_mean[d]);
        s_xhat[rr][d] = xh;
    }
    __syncthreads();

    // thread mapping for phases 3-5: col pair (c0, c0+64), rows g*4 .. g*4+3
    int c0 = t & 63;
    int g  = t >> 6;

    float hreg[4][2];
    float zreg[4][2];

    // ---- phase 3: h = gamma_h * mgn_h[i] ----
    for (int q = 0; q < 4; q++) {
        int rr = g * 4 + q;
        float4 iv[8];
        const float4* ip = (const float4*)(&s_intv[rr][0]);
        #pragma unroll
        for (int k4 = 0; k4 < 8; k4++) iv[k4] = ip[k4];
        int gi = s_idx[rr];
        #pragma unroll
        for (int cc = 0; cc < 2; cc++) {
            int e = c0 + cc * 64;
            const float4* wp = (const float4*)(W_gh + e * D_);
            float s = 0.f;
            #pragma unroll
            for (int k4 = 0; k4 < 8; k4++) {
                float4 w = wp[k4];
                s += iv[k4].x * w.x + iv[k4].y * w.y + iv[k4].z * w.z + iv[k4].w * w.w;
            }
            float gh = expf(-fmaxf(s, 0.f));
            float hv = (gi >= 0) ? gh * mgn_h[(long)gi * HID_ + e] : 0.f;
            hreg[q][cc] = hv;
            s_h[rr][e] = hv;
        }
    }
    __syncthreads();

    // ---- phase 4: z and r ----
    float accz[4][2], accr[4][2];
    #pragma unroll
    for (int cc = 0; cc < 2; cc++) {
        int e = c0 + cc * 64;
        float bzv = bz[e], brv = br[e];
        #pragma unroll
        for (int q = 0; q < 4; q++) { accz[q][cc] = bzv; accr[q][cc] = brv; }
    }
    // X_hat @ W + M @ V part
    for (int d4 = 0; d4 < D_ / 4; d4++) {
        float4 xh4[4], m4[4];
        #pragma unroll
        for (int q = 0; q < 4; q++) {
            int rr = g * 4 + q;
            xh4[q] = ((const float4*)&s_xhat[rr][0])[d4];
            m4[q]  = ((const float4*)&s_M[rr][0])[d4];
        }
        #pragma unroll
        for (int dd = 0; dd < 4; dd++) {
            int d = d4 * 4 + dd;
            #pragma unroll
            for (int cc = 0; cc < 2; cc++) {
                int e = c0 + cc * 64;
                float wz = Wz[d * HID_ + e], vz = Vz[d * HID_ + e];
                float wr = Wr[d * HID_ + e], vr = Vr[d * HID_ + e];
                #pragma unroll
                for (int q = 0; q < 4; q++) {
                    float xh = ((const float*)&xh4[q])[dd];
                    float mm = ((const float*)&m4[q])[dd];
                    accz[q][cc] += xh * wz + mm * vz;
                    accr[q][cc] += xh * wr + mm * vr;
                }
            }
        }
    }
    // h @ U part
    for (int k4 = 0; k4 < HID_ / 4; k4++) {
        float4 h4[4];
        #pragma unroll
        for (int q = 0; q < 4; q++)
            h4[q] = ((const float4*)&s_h[g * 4 + q][0])[k4];
        #pragma unroll
        for (int kk = 0; kk < 4; kk++) {
            int k = k4 * 4 + kk;
            #pragma unroll
            for (int cc = 0; cc < 2; cc++) {
                int e = c0 + cc * 64;
                float uz = Uz[k * HID_ + e], ur = Ur[k * HID_ + e];
                #pragma unroll
                for (int q = 0; q < 4; q++) {
                    float hv = ((const float*)&h4[q])[kk];
                    accz[q][cc] += hv * uz;
                    accr[q][cc] += hv * ur;
                }
            }
        }
    }
    // activations; write r*h to LDS
    #pragma unroll
    for (int q = 0; q < 4; q++) {
        int rr = g * 4 + q;
        #pragma unroll
        for (int cc = 0; cc < 2; cc++) {
            int e = c0 + cc * 64;
            float z  = sigmoidf_(accz[q][cc]);
            float rv = sigmoidf_(accr[q][cc]);
            zreg[q][cc] = z;
            s_rh[rr][e] = rv * hreg[q][cc];
        }
    }
    __syncthreads();

    // ---- phase 5: h_tilde and output ----
    float acch[4][2];
    #pragma unroll
    for (int cc = 0; cc < 2; cc++) {
        int e = c0 + cc * 64;
        float bhv = bh[e];
        #pragma unroll
        for (int q = 0; q < 4; q++) acch[q][cc] = bhv;
    }
    for (int d4 = 0; d4 < D_ / 4; d4++) {
        float4 xh4[4], m4[4];
        #pragma unroll
        for (int q = 0; q < 4; q++) {
            int rr = g * 4 + q;
            xh4[q] = ((const float4*)&s_xhat[rr][0])[d4];
            m4[q]  = ((const float4*)&s_M[rr][0])[d4];
        }
        #pragma unroll
        for (int dd = 0; dd < 4; dd++) {
            int d = d4 * 4 + dd;
            #pragma unroll
            for (int cc = 0; cc < 2; cc++) {
                int e = c0 + cc * 64;
                float wh = Wh[d * HID_ + e], vh = Vh[d * HID_ + e];
                #pragma unroll
                for (int q = 0; q < 4; q++) {
                    float xh = ((const float*)&xh4[q])[dd];
                    float mm = ((const float*)&m4[q])[dd];
                    acch[q][cc] += xh * wh + mm * vh;
                }
            }
        }
    }
    for (int k4 = 0; k4 < HID_ / 4; k4++) {
        float4 rh4[4];
        #pragma unroll
        for (int q = 0; q < 4; q++)
            rh4[q] = ((const float4*)&s_rh[g * 4 + q][0])[k4];
        #pragma unroll
        for (int kk = 0; kk < 4; kk++) {
            int k = k4 * 4 + kk;
            #pragma unroll
            for (int cc = 0; cc < 2; cc++) {
                int e = c0 + cc * 64;
                float uh = Uh[k * HID_ + e];
                #pragma unroll
                for (int q = 0; q < 4; q++) {
                    float rv = ((const float*)&rh4[q])[kk];
                    acch[q][cc] += rv * uh;
                }
            }
        }
    }
    #pragma unroll
    for (int q = 0; q < 4; q++) {
        int gi = s_idx[g * 4 + q];
        if (gi < 0) continue;
        #pragma unroll
        for (int cc = 0; cc < 2; cc++) {
            int e = c0 + cc * 64;
            float ht = tanhf(acch[q][cc]);
            float z  = zreg[q][cc];
            float hn = (1.f - z) * hreg[q][cc] + z * ht;
            out_h[(long)gi * HID_ + e] = hn;
        }
    }
}

extern "C" void kernel_launch(void* const* d_in, const int* in_sizes, int n_in,
                              void* d_out, int out_size, void* d_ws, size_t ws_size,
                              hipStream_t stream)
{
    const float* ct     = (const float*)d_in[0];
    const float* mgn_h  = (const float*)d_in[1];
    const float* X_obs  = (const float*)d_in[2];
    const float* M_obs  = (const float*)d_in[3];
    const int*   i_obs  = (const int*)d_in[4];
    const float* last_x = (const float*)d_in[5];
    const float* last_t = (const float*)d_in[6];
    const float* W_gx   = (const float*)d_in[7];
    const float* W_gh   = (const float*)d_in[8];
    const float* Wz = (const float*)d_in[9];
    const float* Vz = (const float*)d_in[10];
    const float* Uz = (const float*)d_in[11];
    const float* bz = (const float*)d_in[12];
    const float* Wr = (const float*)d_in[13];
    const float* Vr = (const float*)d_in[14];
    const float* Ur = (const float*)d_in[15];
    const float* br = (const float*)d_in[16];
    const float* Wh = (const float*)d_in[17];
    const float* Vh = (const float*)d_in[18];
    const float* Uh = (const float*)d_in[19];
    const float* bh = (const float*)d_in[20];

    int n_obs = in_sizes[4];
    int N = in_sizes[1] / HID_;

    float* out_h  = (float*)d_out;
    float* out_lx = out_h + (long)N * HID_;
    float* out_lt = out_lx + (long)N * D_;

    float* partials = (float*)d_ws;           // 128*64 floats = 32 KB
    float* mean_x   = partials + 128 * 64;    // 32 floats

    int chunk = (n_obs + 127) / 128;
    k_mean1<<<128, 256, 0, stream>>>(X_obs, M_obs, partials, n_obs, chunk);
    k_mean2<<<1, 64, 0, stream>>>(partials, mean_x, 128);
    k_copy<<<2048, 256, 0, stream>>>((const float4*)mgn_h, (const float4*)last_x, (const float4*)last_t,
                                     (float4*)out_h, (float4*)out_lx, (float4*)out_lt, N);
    int nblk = (n_obs + ROWS - 1) / ROWS;
    k_main<<<nblk, 256, 0, stream>>>(ct, mgn_h, X_obs, M_obs, i_obs, last_x, last_t,
                                     W_gx, W_gh, Wz, Vz, Uz, bz, Wr, Vr, Ur, br,
                                     Wh, Vh, Uh, bh,
                                     mean_x, out_h, out_lx, out_lt, n_obs);
}

// Round 3
// 278.473 us; speedup vs baseline: 2.1015x; 2.1015x over previous
//
#include <hip/hip_runtime.h>

#define D_ 32
#define HID_ 128
#define ROWS 32

typedef __attribute__((ext_vector_type(8))) short bf16x8;
typedef __attribute__((ext_vector_type(4))) float f32x4;

__device__ __forceinline__ unsigned short f2bf(float x) {
    unsigned u = __float_as_uint(x);
    u += 0x7FFFu + ((u >> 16) & 1u);
    return (unsigned short)(u >> 16);
}
__device__ __forceinline__ float b2f(unsigned short h) {
    return __uint_as_float(((unsigned)h) << 16);
}
__device__ __forceinline__ float sigmoidf_(float x) {
    return 1.0f / (1.0f + expf(-x));
}

// ---------------- weight packer: bf16 hi/lo planes in B-fragment lane order ----------------
// fragment slot layout: elem index = ((tn*KS + ks)*64 + lane)*8 + j
// maps to B[k][n] with k = ks*32 + (lane>>4)*8 + j, n = tn*16 + (lane&15)
__global__ __launch_bounds__(256) void k_prep(
    const float* __restrict__ W_gx, const float* __restrict__ W_gh,
    const float* __restrict__ Wz, const float* __restrict__ Vz, const float* __restrict__ Uz,
    const float* __restrict__ Wr, const float* __restrict__ Vr, const float* __restrict__ Ur,
    const float* __restrict__ Wh, const float* __restrict__ Vh, const float* __restrict__ Uh,
    short* __restrict__ gxh, short* __restrict__ gxl,
    short* __restrict__ ghh, short* __restrict__ ghl,
    short* __restrict__ zrh, short* __restrict__ zrl,
    short* __restrict__ h3h, short* __restrict__ h3l)
{
    int tid = blockIdx.x * 256 + threadIdx.x;
    if (tid >= 78848) return;
    float v = 0.f;
    short* ph;
    short* pl;
    int local;
    if (tid < 1024) {                       // Bgx: K=32, N=32 (B = W_gx^T)
        local = tid;
        int j = local & 7, lane = (local >> 3) & 63, tn = local >> 9;
        int k = ((lane >> 4) << 3) + j;
        int n = tn * 16 + (lane & 15);
        v = W_gx[n * D_ + k];
        ph = gxh; pl = gxl;
    } else if (tid < 5120) {                // Bgh: K=32, N=128 (B = W_gh^T)
        local = tid - 1024;
        int j = local & 7, lane = (local >> 3) & 63, tn = local >> 9;
        int k = ((lane >> 4) << 3) + j;
        int n = tn * 16 + (lane & 15);
        v = W_gh[n * D_ + k];
        ph = ghh; pl = ghl;
    } else if (tid < 54272) {               // Bzr: K=192 [xhat|M|h], N=256 [z|r]
        local = tid - 5120;
        int j = local & 7, lane = (local >> 3) & 63, fs = local >> 9;
        int ks = fs % 6, tn = fs / 6;
        int k = ks * 32 + ((lane >> 4) << 3) + j;
        int n = tn * 16 + (lane & 15);
        const float *W, *V, *U;
        int nc;
        if (n < 128) { W = Wz; V = Vz; U = Uz; nc = n; }
        else         { W = Wr; V = Vr; U = Ur; nc = n - 128; }
        if (k < 32)       v = W[k * HID_ + nc];
        else if (k < 64)  v = V[(k - 32) * HID_ + nc];
        else              v = U[(k - 64) * HID_ + nc];
        ph = zrh; pl = zrl;
    } else {                                // Bh3: K=192 [xhat|M|rh], N=128
        local = tid - 54272;
        int j = local & 7, lane = (local >> 3) & 63, fs = local >> 9;
        int ks = fs % 6, tn = fs / 6;
        int k = ks * 32 + ((lane >> 4) << 3) + j;
        int n = tn * 16 + (lane & 15);
        if (k < 32)       v = Wh[k * HID_ + n];
        else if (k < 64)  v = Vh[(k - 32) * HID_ + n];
        else              v = Uh[(k - 64) * HID_ + n];
        ph = h3h; pl = h3l;
    }
    unsigned short hi = f2bf(v);
    float fh = b2f(hi);
    unsigned short lo = f2bf(v - fh);
    ph[local] = (short)hi;
    pl[local] = (short)lo;
}

// ---------------- mean reduction, stage 1 ----------------
__global__ __launch_bounds__(256) void k_mean1(
    const float* __restrict__ X_obs, const float* __restrict__ M_obs,
    float* __restrict__ partials, int n_obs, int chunk)
{
    int d = threadIdx.x & 31;
    int sub = threadIdx.x >> 5;
    int start = blockIdx.x * chunk;
    int end = start + chunk;
    if (end > n_obs) end = n_obs;
    float sx = 0.f, sm = 0.f;
    for (int j = start + sub; j < end; j += 8) {
        sx += X_obs[j * D_ + d];
        sm += M_obs[j * D_ + d] + 1e-6f;
    }
    __shared__ float redx[8][33];
    __shared__ float redm[8][33];
    redx[sub][d] = sx;
    redm[sub][d] = sm;
    __syncthreads();
    if (sub == 0) {
        float tx = 0.f, tm = 0.f;
        #pragma unroll
        for (int s = 0; s < 8; s++) { tx += redx[s][d]; tm += redm[s][d]; }
        partials[blockIdx.x * 64 + d] = tx;
        partials[blockIdx.x * 64 + 32 + d] = tm;
    }
}

// ---------------- mean reduction, stage 2 ----------------
__global__ void k_mean2(const float* __restrict__ partials, float* __restrict__ mean_x, int nblk)
{
    int d = threadIdx.x;
    if (d < 32) {
        float sx = 0.f, sm = 0.f;
        for (int b = 0; b < nblk; b++) {
            sx += partials[b * 64 + d];
            sm += partials[b * 64 + 32 + d];
        }
        mean_x[d] = sx / sm;
    }
}

// ---------------- copy-through of all rows ----------------
__global__ __launch_bounds__(256) void k_copy(
    const float4* __restrict__ mgn_h, const float4* __restrict__ last_x, const float4* __restrict__ last_t,
    float4* __restrict__ out_h, float4* __restrict__ out_lx, float4* __restrict__ out_lt,
    int n)
{
    long nh = (long)n * (HID_ / 4);
    long nx = (long)n * (D_ / 4);
    long total = nh + 2 * nx;
    for (long i = blockIdx.x * (long)blockDim.x + threadIdx.x; i < total;
         i += (long)gridDim.x * blockDim.x) {
        if (i < nh)            out_h[i] = mgn_h[i];
        else if (i < nh + nx)  out_lx[i - nh] = last_x[i - nh];
        else                   out_lt[i - nh - nx] = last_t[i - nh - nx];
    }
}

// ---------------- fused GRU-D main kernel: MFMA path, 32 rows / 256-thread block ----------------
__global__ __launch_bounds__(256, 2) void k_main(
    const float* __restrict__ ct_p,
    const float* __restrict__ mgn_h,
    const float* __restrict__ X_obs,
    const float* __restrict__ M_obs,
    const int*   __restrict__ i_obs,
    const float* __restrict__ last_x,
    const float* __restrict__ last_t,
    const float* __restrict__ bz, const float* __restrict__ br, const float* __restrict__ bh,
    const float* __restrict__ mean_x,
    const short* __restrict__ gxh, const short* __restrict__ gxl,
    const short* __restrict__ ghh, const short* __restrict__ ghl,
    const short* __restrict__ zrh, const short* __restrict__ zrl,
    const short* __restrict__ h3h, const short* __restrict__ h3l,
    float* __restrict__ out_h, float* __restrict__ out_lx, float* __restrict__ out_lt,
    int n_obs)
{
    // bf16 hi/lo A-operand planes (pre-split once at write time)
    __shared__ short sh_h_hi[ROWS][136],  sh_h_lo[ROWS][136];
    __shared__ short sh_rh_hi[ROWS][136], sh_rh_lo[ROWS][136];
    __shared__ short sh_iv_hi[ROWS][40],  sh_iv_lo[ROWS][40];
    __shared__ short sh_M_hi[ROWS][40];
    __shared__ short sh_xh_hi[ROWS][40],  sh_xh_lo[ROWS][40];
    __shared__ float s_X[ROWS][36], s_lxn[ROWS][36];
    __shared__ float s_mgn[ROWS][130];    // mgn gather; reused as fp32 h after P2
    __shared__ float s_mean[D_];
    __shared__ int   s_idx[ROWS];

    const int t = threadIdx.x;
    const int row0 = blockIdx.x * ROWS;

    if (t < ROWS) {
        int j = row0 + t;
        s_idx[t] = (j < n_obs) ? i_obs[j] : -1;
    }
    if (t >= 32 && t < 64) s_mean[t - 32] = mean_x[t - 32];
    __syncthreads();
    const float ctv = ct_p[0];

    // ---- P1: gather + pointwise last_x/last_t update; stage interval/M/X/lxn ----
    #pragma unroll
    for (int it = 0; it < 4; it++) {
        int u = t + it * 256;                 // 32*32 = 1024 items
        int rr = u >> 5, d = u & 31;
        int gi = s_idx[rr];
        float itv = 0.f, Mm = 0.f, Xv = 0.f, lxn = 0.f;
        if (gi >= 0) {
            int j = row0 + rr;
            Xv = X_obs[j * D_ + d];
            Mm = M_obs[j * D_ + d];
            float lx = last_x[(long)gi * D_ + d];
            float lt = last_t[(long)gi * D_ + d];
            itv = ctv - lt;
            lxn = lx * (1.f - Mm) + Xv * Mm;
            float ltn = lt * (1.f - Mm) + ctv * Mm;
            out_lx[(long)gi * D_ + d] = lxn;
            out_lt[(long)gi * D_ + d] = ltn;
        }
        unsigned short ih = f2bf(itv);
        sh_iv_hi[rr][d] = (short)ih;
        sh_iv_lo[rr][d] = (short)f2bf(itv - b2f(ih));
        sh_M_hi[rr][d]  = (short)f2bf(Mm);     // exact (0/1)
        s_X[rr][d]   = Xv;
        s_lxn[rr][d] = lxn;
    }
    // ---- P1b: coalesced gather of mgn_h rows ----
    #pragma unroll
    for (int it = 0; it < 16; it++) {
        int u = t + it * 256;                 // 32*128 = 4096 items
        int rr = u >> 7, c = u & 127;
        int gi = s_idx[rr];
        s_mgn[rr][c] = (gi >= 0) ? mgn_h[(long)gi * HID_ + c] : 0.f;
    }
    __syncthreads();

    const int wave = t >> 6;
    const int lane = t & 63;
    const int lo4  = lane & 15;     // A-row / C-col low index
    const int hi2  = lane >> 4;     // quarter index
    const bf16x8* vgxh = (const bf16x8*)gxh;
    const bf16x8* vgxl = (const bf16x8*)gxl;
    const bf16x8* vghh = (const bf16x8*)ghh;
    const bf16x8* vghl = (const bf16x8*)ghl;
    const bf16x8* vzrh = (const bf16x8*)zrh;
    const bf16x8* vzrl = (const bf16x8*)zrl;
    const bf16x8* vh3h = (const bf16x8*)h3h;
    const bf16x8* vh3l = (const bf16x8*)h3l;

    // ---- P2: gamma GEMMs (K=32). tiles 0-7 = gamma_h (128 cols), 8-9 = gamma_x (32 cols) ----
    for (int tn = wave; tn < 10; tn += 4) {
        bool isH = (tn < 8);
        bf16x8 bhi = isH ? vghh[tn * 64 + lane] : vgxh[(tn - 8) * 64 + lane];
        bf16x8 blo = isH ? vghl[tn * 64 + lane] : vgxl[(tn - 8) * 64 + lane];
        #pragma unroll
        for (int si = 0; si < 2; si++) {
            int ar = si * 16 + lo4;
            bf16x8 ahi = *(const bf16x8*)&sh_iv_hi[ar][hi2 * 8];
            bf16x8 alo = *(const bf16x8*)&sh_iv_lo[ar][hi2 * 8];
            f32x4 acc = {0.f, 0.f, 0.f, 0.f};
            acc = __builtin_amdgcn_mfma_f32_16x16x32_bf16(ahi, bhi, acc, 0, 0, 0);
            acc = __builtin_amdgcn_mfma_f32_16x16x32_bf16(ahi, blo, acc, 0, 0, 0);
            acc = __builtin_amdgcn_mfma_f32_16x16x32_bf16(alo, bhi, acc, 0, 0, 0);
            #pragma unroll
            for (int q = 0; q < 4; q++) {
                int r = si * 16 + hi2 * 4 + q;
                float g = expf(-fmaxf(acc[q], 0.f));
                if (isH) {
                    int c = tn * 16 + lo4;
                    float hv = g * s_mgn[r][c];
                    unsigned short hh = f2bf(hv);
                    sh_h_hi[r][c] = (short)hh;
                    sh_h_lo[r][c] = (short)f2bf(hv - b2f(hh));
                    s_mgn[r][c] = hv;          // reuse: exact fp32 h
                } else {
                    int c = (tn - 8) * 16 + lo4;
                    float Mv = b2f((unsigned short)sh_M_hi[r][c]);
                    float xh = Mv * s_X[r][c]
                             + (1.f - Mv) * (g * s_lxn[r][c] + (1.f - g) * s_mean[c]);
                    unsigned short xhh = f2bf(xh);
                    sh_xh_hi[r][c] = (short)xhh;
                    sh_xh_lo[r][c] = (short)f2bf(xh - b2f(xhh));
                }
            }
        }
    }
    __syncthreads();

    // ---- P3: z/r GEMM. wave tiles: z {wave, wave+4}, r {wave+8, wave+12}; K = 192 ----
    f32x4 accA[4][2];
    #pragma unroll
    for (int ti = 0; ti < 4; ti++)
        #pragma unroll
        for (int si = 0; si < 2; si++)
            accA[ti][si] = (f32x4){0.f, 0.f, 0.f, 0.f};

    #pragma unroll
    for (int ks = 0; ks < 6; ks++) {
        bf16x8 Ah[2], Al[2];
        bool hasLo = (ks != 1);
        #pragma unroll
        for (int si = 0; si < 2; si++) {
            int ar = si * 16 + lo4;
            if (ks == 0) {
                Ah[si] = *(const bf16x8*)&sh_xh_hi[ar][hi2 * 8];
                Al[si] = *(const bf16x8*)&sh_xh_lo[ar][hi2 * 8];
            } else if (ks == 1) {
                Ah[si] = *(const bf16x8*)&sh_M_hi[ar][hi2 * 8];
                Al[si] = Ah[si]; // unused
            } else {
                int ko = (ks - 2) * 32 + hi2 * 8;
                Ah[si] = *(const bf16x8*)&sh_h_hi[ar][ko];
                Al[si] = *(const bf16x8*)&sh_h_lo[ar][ko];
            }
        }
        #pragma unroll
        for (int ti = 0; ti < 4; ti++) {
            int tn = wave + ti * 4;
            int slot = (tn * 6 + ks) * 64 + lane;
            bf16x8 bhi = vzrh[slot];
            bf16x8 blo = vzrl[slot];
            #pragma unroll
            for (int si = 0; si < 2; si++) {
                f32x4 a = accA[ti][si];
                a = __builtin_amdgcn_mfma_f32_16x16x32_bf16(Ah[si], bhi, a, 0, 0, 0);
                a = __builtin_amdgcn_mfma_f32_16x16x32_bf16(Ah[si], blo, a, 0, 0, 0);
                if (hasLo)
                    a = __builtin_amdgcn_mfma_f32_16x16x32_bf16(Al[si], bhi, a, 0, 0, 0);
                accA[ti][si] = a;
            }
        }
    }
    // post: z -> registers, r -> r*h planes
    float zreg[2][2][4];
    #pragma unroll
    for (int ti = 0; ti < 2; ti++) {
        int c = (wave + ti * 4) * 16 + lo4;
        float bzv = bz[c];
        #pragma unroll
        for (int si = 0; si < 2; si++)
            #pragma unroll
            for (int q = 0; q < 4; q++)
                zreg[ti][si][q] = sigmoidf_(accA[ti][si][q] + bzv);
    }
    #pragma unroll
    for (int ti = 2; ti < 4; ti++) {
        int tn = wave + ti * 4;
        int c = (tn - 8) * 16 + lo4;
        float brv = br[c];
        #pragma unroll
        for (int si = 0; si < 2; si++) {
            #pragma unroll
            for (int q = 0; q < 4; q++) {
                int r = si * 16 + hi2 * 4 + q;
                float rv = sigmoidf_(accA[ti][si][q] + brv);
                float rh = rv * s_mgn[r][c];
                unsigned short rhh = f2bf(rh);
                sh_rh_hi[r][c] = (short)rhh;
                sh_rh_lo[r][c] = (short)f2bf(rh - b2f(rhh));
            }
        }
    }
    __syncthreads();

    // ---- P4: h_tilde GEMM (tiles {wave, wave+4}, same cols as z) + output ----
    f32x4 accB[2][2];
    #pragma unroll
    for (int ti = 0; ti < 2; ti++)
        #pragma unroll
        for (int si = 0; si < 2; si++)
            accB[ti][si] = (f32x4){0.f, 0.f, 0.f, 0.f};

    #pragma unroll
    for (int ks = 0; ks < 6; ks++) {
        bf16x8 Ah[2], Al[2];
        bool hasLo = (ks != 1);
        #pragma unroll
        for (int si = 0; si < 2; si++) {
            int ar = si * 16 + lo4;
            if (ks == 0) {
                Ah[si] = *(const bf16x8*)&sh_xh_hi[ar][hi2 * 8];
                Al[si] = *(const bf16x8*)&sh_xh_lo[ar][hi2 * 8];
            } else if (ks == 1) {
                Ah[si] = *(const bf16x8*)&sh_M_hi[ar][hi2 * 8];
                Al[si] = Ah[si];
            } else {
                int ko = (ks - 2) * 32 + hi2 * 8;
                Ah[si] = *(const bf16x8*)&sh_rh_hi[ar][ko];
                Al[si] = *(const bf16x8*)&sh_rh_lo[ar][ko];
            }
        }
        #pragma unroll
        for (int ti = 0; ti < 2; ti++) {
            int tn = wave + ti * 4;
            int slot = (tn * 6 + ks) * 64 + lane;
            bf16x8 bhi = vh3h[slot];
            bf16x8 blo = vh3l[slot];
            #pragma unroll
            for (int si = 0; si < 2; si++) {
                f32x4 a = accB[ti][si];
                a = __builtin_amdgcn_mfma_f32_16x16x32_bf16(Ah[si], bhi, a, 0, 0, 0);
                a = __builtin_amdgcn_mfma_f32_16x16x32_bf16(Ah[si], blo, a, 0, 0, 0);
                if (hasLo)
                    a = __builtin_amdgcn_mfma_f32_16x16x32_bf16(Al[si], bhi, a, 0, 0, 0);
                accB[ti][si] = a;
            }
        }
    }
    #pragma unroll
    for (int ti = 0; ti < 2; ti++) {
        int c = (wave + ti * 4) * 16 + lo4;
        float bhv = bh[c];
        #pragma unroll
        for (int si = 0; si < 2; si++) {
            #pragma unroll
            for (int q = 0; q < 4; q++) {
                int r = si * 16 + hi2 * 4 + q;
                int gi = s_idx[r];
                if (gi < 0) continue;
                float ht = tanhf(accB[ti][si][q] + bhv);
                float hv = s_mgn[r][c];
                float z  = zreg[ti][si][q];
                out_h[(long)gi * HID_ + c] = (1.f - z) * hv + z * ht;
            }
        }
    }
}

extern "C" void kernel_launch(void* const* d_in, const int* in_sizes, int n_in,
                              void* d_out, int out_size, void* d_ws, size_t ws_size,
                              hipStream_t stream)
{
    const float* ct     = (const float*)d_in[0];
    const float* mgn_h  = (const float*)d_in[1];
    const float* X_obs  = (const float*)d_in[2];
    const float* M_obs  = (const float*)d_in[3];
    const int*   i_obs  = (const int*)d_in[4];
    const float* last_x = (const float*)d_in[5];
    const float* last_t = (const float*)d_in[6];
    const float* W_gx   = (const float*)d_in[7];
    const float* W_gh   = (const float*)d_in[8];
    const float* Wz = (const float*)d_in[9];
    const float* Vz = (const float*)d_in[10];
    const float* Uz = (const float*)d_in[11];
    const float* bz = (const float*)d_in[12];
    const float* Wr = (const float*)d_in[13];
    const float* Vr = (const float*)d_in[14];
    const float* Ur = (const float*)d_in[15];
    const float* br = (const float*)d_in[16];
    const float* Wh = (const float*)d_in[17];
    const float* Vh = (const float*)d_in[18];
    const float* Uh = (const float*)d_in[19];
    const float* bh = (const float*)d_in[20];

    int n_obs = in_sizes[4];
    int N = in_sizes[1] / HID_;

    float* out_h  = (float*)d_out;
    float* out_lx = out_h + (long)N * HID_;
    float* out_lt = out_lx + (long)N * D_;

    char* w = (char*)d_ws;
    float* partials = (float*)w;                       // 32768 B
    float* mean_x   = (float*)(w + 32768);             // 128 B
    short* gxh = (short*)(w + 32896);                  // 2048 B
    short* gxl = (short*)(w + 32896 + 2048);
    short* ghh = (short*)(w + 36992);                  // 8192 B
    short* ghl = (short*)(w + 36992 + 8192);
    short* zrh = (short*)(w + 53376);                  // 98304 B
    short* zrl = (short*)(w + 53376 + 98304);
    short* h3h = (short*)(w + 249984);                 // 49152 B
    short* h3l = (short*)(w + 249984 + 49152);

    k_prep<<<308, 256, 0, stream>>>(W_gx, W_gh, Wz, Vz, Uz, Wr, Vr, Ur, Wh, Vh, Uh,
                                    gxh, gxl, ghh, ghl, zrh, zrl, h3h, h3l);
    int chunk = (n_obs + 127) / 128;
    k_mean1<<<128, 256, 0, stream>>>(X_obs, M_obs, partials, n_obs, chunk);
    k_mean2<<<1, 64, 0, stream>>>(partials, mean_x, 128);
    k_copy<<<2048, 256, 0, stream>>>((const float4*)mgn_h, (const float4*)last_x, (const float4*)last_t,
                                     (float4*)out_h, (float4*)out_lx, (float4*)out_lt, N);
    int nblk = (n_obs + ROWS - 1) / ROWS;
    k_main<<<nblk, 256, 0, stream>>>(ct, mgn_h, X_obs, M_obs, i_obs, last_x, last_t,
                                     bz, br, bh, mean_x,
                                     gxh, gxl, ghh, ghl, zrh, zrl, h3h, h3l,
                                     out_h, out_lx, out_lt, n_obs);
}

// Round 4
// 207.570 us; speedup vs baseline: 2.8194x; 1.3416x over previous
//
#include <hip/hip_runtime.h>
#include <hip/hip_bf16.h>

#define D_ 32
#define HID_ 128
#define ROWS 32

typedef __attribute__((ext_vector_type(8))) short bf16x8;
typedef __attribute__((ext_vector_type(4))) float f32x4;
typedef __attribute__((ext_vector_type(4))) unsigned short us4;

__device__ __forceinline__ unsigned short bfh(float v) {
    __hip_bfloat16 b = __float2bfloat16(v);
    unsigned short u;
    __builtin_memcpy(&u, &b, 2);
    return u;
}
__device__ __forceinline__ float bfh2f(unsigned short u) {
    return __uint_as_float(((unsigned)u) << 16);
}
__device__ __forceinline__ float fsig(float x) {
    return __fdividef(1.0f, 1.0f + __expf(-x));
}
__device__ __forceinline__ float ftanh(float x) {
    return 1.0f - __fdividef(2.0f, __expf(2.0f * x) + 1.0f);
}

// ---------------- weight packer: bf16 hi/lo planes in B-fragment lane order ----------------
// elem index = ((tn*KS + ks)*64 + lane)*8 + j  ->  B[k][n], k = ks*32 + (lane>>4)*8 + j,
// n = tn*16 + (lane&15)
__global__ __launch_bounds__(256) void k_prep(
    const float* __restrict__ W_gx, const float* __restrict__ W_gh,
    const float* __restrict__ Wz, const float* __restrict__ Vz, const float* __restrict__ Uz,
    const float* __restrict__ Wr, const float* __restrict__ Vr, const float* __restrict__ Ur,
    const float* __restrict__ Wh, const float* __restrict__ Vh, const float* __restrict__ Uh,
    short* __restrict__ gxh, short* __restrict__ gxl,
    short* __restrict__ ghh, short* __restrict__ ghl,
    short* __restrict__ zrh, short* __restrict__ zrl,
    short* __restrict__ h3h, short* __restrict__ h3l)
{
    int tid = blockIdx.x * 256 + threadIdx.x;
    if (tid >= 78848) return;
    float v = 0.f;
    short* ph;
    short* pl;
    int local;
    if (tid < 1024) {                       // Bgx: K=32, N=32 (B = W_gx^T)
        local = tid;
        int j = local & 7, lane = (local >> 3) & 63, tn = local >> 9;
        int k = ((lane >> 4) << 3) + j;
        int n = tn * 16 + (lane & 15);
        v = W_gx[n * D_ + k];
        ph = gxh; pl = gxl;
    } else if (tid < 5120) {                // Bgh: K=32, N=128 (B = W_gh^T)
        local = tid - 1024;
        int j = local & 7, lane = (local >> 3) & 63, tn = local >> 9;
        int k = ((lane >> 4) << 3) + j;
        int n = tn * 16 + (lane & 15);
        v = W_gh[n * D_ + k];
        ph = ghh; pl = ghl;
    } else if (tid < 54272) {               // Bzr: K=192 [xhat|M|h], N=256 [z|r]
        local = tid - 5120;
        int j = local & 7, lane = (local >> 3) & 63, fs = local >> 9;
        int ks = fs % 6, tn = fs / 6;
        int k = ks * 32 + ((lane >> 4) << 3) + j;
        int n = tn * 16 + (lane & 15);
        const float *W, *V, *U;
        int nc;
        if (n < 128) { W = Wz; V = Vz; U = Uz; nc = n; }
        else         { W = Wr; V = Vr; U = Ur; nc = n - 128; }
        if (k < 32)       v = W[k * HID_ + nc];
        else if (k < 64)  v = V[(k - 32) * HID_ + nc];
        else              v = U[(k - 64) * HID_ + nc];
        ph = zrh; pl = zrl;
    } else {                                // Bh3: K=192 [xhat|M|rh], N=128
        local = tid - 54272;
        int j = local & 7, lane = (local >> 3) & 63, fs = local >> 9;
        int ks = fs % 6, tn = fs / 6;
        int k = ks * 32 + ((lane >> 4) << 3) + j;
        int n = tn * 16 + (lane & 15);
        if (k < 32)       v = Wh[k * HID_ + n];
        else if (k < 64)  v = Vh[(k - 32) * HID_ + n];
        else              v = Uh[(k - 64) * HID_ + n];
        ph = h3h; pl = h3l;
    }
    unsigned short hi = bfh(v);
    unsigned short lo = bfh(v - bfh2f(hi));
    ph[local] = (short)hi;
    pl[local] = (short)lo;
}

// ---------------- mean reduction, stage 1 ----------------
__global__ __launch_bounds__(256) void k_mean1(
    const float* __restrict__ X_obs, const float* __restrict__ M_obs,
    float* __restrict__ partials, int n_obs, int chunk)
{
    int d = threadIdx.x & 31;
    int sub = threadIdx.x >> 5;
    int start = blockIdx.x * chunk;
    int end = start + chunk;
    if (end > n_obs) end = n_obs;
    float sx = 0.f, sm = 0.f;
    for (int j = start + sub; j < end; j += 8) {
        sx += X_obs[j * D_ + d];
        sm += M_obs[j * D_ + d] + 1e-6f;
    }
    __shared__ float redx[8][33];
    __shared__ float redm[8][33];
    redx[sub][d] = sx;
    redm[sub][d] = sm;
    __syncthreads();
    if (sub == 0) {
        float tx = 0.f, tm = 0.f;
        #pragma unroll
        for (int s = 0; s < 8; s++) { tx += redx[s][d]; tm += redm[s][d]; }
        partials[blockIdx.x * 64 + d] = tx;
        partials[blockIdx.x * 64 + 32 + d] = tm;
    }
}

// ---------------- mean reduction, stage 2 ----------------
__global__ void k_mean2(const float* __restrict__ partials, float* __restrict__ mean_x, int nblk)
{
    int d = threadIdx.x;
    if (d < 32) {
        float sx = 0.f, sm = 0.f;
        for (int b = 0; b < nblk; b++) {
            sx += partials[b * 64 + d];
            sm += partials[b * 64 + 32 + d];
        }
        mean_x[d] = sx / sm;
    }
}

// ---------------- bitmap: mark observed rows ----------------
__global__ __launch_bounds__(256) void k_bitset(
    const int* __restrict__ i_obs, unsigned* __restrict__ bm, int n_obs)
{
    int i = blockIdx.x * 256 + threadIdx.x;
    if (i < n_obs) {
        int gi = i_obs[i];
        atomicOr(&bm[gi >> 5], 1u << (gi & 31));
    }
}

// ---------------- copy-through of UNOBSERVED rows only ----------------
__global__ __launch_bounds__(256) void k_copy(
    const float4* __restrict__ mgn_h, const float4* __restrict__ last_x, const float4* __restrict__ last_t,
    float4* __restrict__ out_h, float4* __restrict__ out_lx, float4* __restrict__ out_lt,
    const unsigned* __restrict__ bm, int n)
{
    long nh = (long)n * (HID_ / 4);
    long nx = (long)n * (D_ / 4);
    long total = nh + 2 * nx;
    for (long i = blockIdx.x * (long)blockDim.x + threadIdx.x; i < total;
         i += (long)gridDim.x * blockDim.x) {
        if (i < nh) {
            int row = (int)(i >> 5);
            if (!((bm[row >> 5] >> (row & 31)) & 1u)) out_h[i] = mgn_h[i];
        } else if (i < nh + nx) {
            long j = i - nh;
            int row = (int)(j >> 3);
            if (!((bm[row >> 5] >> (row & 31)) & 1u)) out_lx[j] = last_x[j];
        } else {
            long j = i - nh - nx;
            int row = (int)(j >> 3);
            if (!((bm[row >> 5] >> (row & 31)) & 1u)) out_lt[j] = last_t[j];
        }
    }
}

// ---------------- fused GRU-D main kernel: MFMA path, 32 rows / 256-thread block ----------------
__global__ __launch_bounds__(256, 3) void k_main(
    const float* __restrict__ ct_p,
    const float* __restrict__ mgn_h,
    const float* __restrict__ X_obs,
    const float* __restrict__ M_obs,
    const int*   __restrict__ i_obs,
    const float* __restrict__ last_x,
    const float* __restrict__ last_t,
    const float* __restrict__ bz, const float* __restrict__ br, const float* __restrict__ bh,
    const float* __restrict__ mean_x,
    const short* __restrict__ gxh, const short* __restrict__ gxl,
    const short* __restrict__ ghh, const short* __restrict__ ghl,
    const short* __restrict__ zrh, const short* __restrict__ zrl,
    const short* __restrict__ h3h, const short* __restrict__ h3l,
    float* __restrict__ out_h, float* __restrict__ out_lx, float* __restrict__ out_lt,
    int n_obs)
{
    // bf16 hi/lo A-operand planes. sh_h planes are overwritten with r*h after P3.
    __shared__ unsigned short sh_h_hi[ROWS][136], sh_h_lo[ROWS][136];
    __shared__ unsigned short sh_iv_hi[ROWS][40], sh_iv_lo[ROWS][40];
    __shared__ unsigned short sh_M[ROWS][40];
    __shared__ unsigned short sh_xh_hi[ROWS][40], sh_xh_lo[ROWS][40];
    __shared__ float s_X[ROWS][33], s_lxn[ROWS][33];
    __shared__ float s_mean[D_];
    __shared__ int   s_idx[ROWS];
    // total LDS = 17408 + 12800 + 8448 + 128 + 128 = 38912 B -> >=3 blocks/CU

    const int t = threadIdx.x;
    const int row0 = blockIdx.x * ROWS;
    const int wave = t >> 6, lane = t & 63;
    const int lo4 = lane & 15, hi2 = lane >> 4;

    if (t < ROWS) {
        int j = row0 + t;
        s_idx[t] = (j < n_obs) ? i_obs[j] : -1;
    }
    if (t >= 64 && t < 96) s_mean[t - 64] = mean_x[t - 64];
    __syncthreads();
    const float ctv = ct_p[0];

    // ---- prefetch mgn_h values this wave will own (cols of tiles {wave, wave+4}) ----
    float hreg[2][2][4];
    #pragma unroll
    for (int ti = 0; ti < 2; ti++) {
        int c = (wave + ti * 4) * 16 + lo4;
        #pragma unroll
        for (int si = 0; si < 2; si++) {
            #pragma unroll
            for (int q = 0; q < 4; q++) {
                int r = si * 16 + hi2 * 4 + q;
                int gi = s_idx[r];
                hreg[ti][si][q] = (gi >= 0) ? mgn_h[(long)gi * HID_ + c] : 0.f;
            }
        }
    }

    // ---- P1: vectorized pointwise updates; stage interval/M/X/lxn ----
    {
        int rr = t >> 3, c4 = t & 7, d0 = c4 * 4;
        int gi = s_idx[rr];
        float4 Xv = make_float4(0.f, 0.f, 0.f, 0.f);
        float4 Mm = Xv, itv = Xv, lxn = Xv;
        if (gi >= 0) {
            int j = row0 + rr;
            Xv = ((const float4*)X_obs)[j * 8 + c4];
            Mm = ((const float4*)M_obs)[j * 8 + c4];
            float4 lx = ((const float4*)last_x)[(long)gi * 8 + c4];
            float4 lt = ((const float4*)last_t)[(long)gi * 8 + c4];
            float4 ltn;
            itv.x = ctv - lt.x; lxn.x = lx.x * (1.f - Mm.x) + Xv.x * Mm.x; ltn.x = lt.x * (1.f - Mm.x) + ctv * Mm.x;
            itv.y = ctv - lt.y; lxn.y = lx.y * (1.f - Mm.y) + Xv.y * Mm.y; ltn.y = lt.y * (1.f - Mm.y) + ctv * Mm.y;
            itv.z = ctv - lt.z; lxn.z = lx.z * (1.f - Mm.z) + Xv.z * Mm.z; ltn.z = lt.z * (1.f - Mm.z) + ctv * Mm.z;
            itv.w = ctv - lt.w; lxn.w = lx.w * (1.f - Mm.w) + Xv.w * Mm.w; ltn.w = lt.w * (1.f - Mm.w) + ctv * Mm.w;
            ((float4*)out_lx)[(long)gi * 8 + c4] = lxn;
            ((float4*)out_lt)[(long)gi * 8 + c4] = ltn;
        }
        us4 ih, il, mh;
        {
            unsigned short h0 = bfh(itv.x); ih.x = h0; il.x = bfh(itv.x - bfh2f(h0)); mh.x = bfh(Mm.x);
            unsigned short h1 = bfh(itv.y); ih.y = h1; il.y = bfh(itv.y - bfh2f(h1)); mh.y = bfh(Mm.y);
            unsigned short h2 = bfh(itv.z); ih.z = h2; il.z = bfh(itv.z - bfh2f(h2)); mh.z = bfh(Mm.z);
            unsigned short h3 = bfh(itv.w); ih.w = h3; il.w = bfh(itv.w - bfh2f(h3)); mh.w = bfh(Mm.w);
        }
        *(us4*)&sh_iv_hi[rr][d0] = ih;
        *(us4*)&sh_iv_lo[rr][d0] = il;
        *(us4*)&sh_M[rr][d0]     = mh;
        s_X[rr][d0 + 0] = Xv.x; s_X[rr][d0 + 1] = Xv.y; s_X[rr][d0 + 2] = Xv.z; s_X[rr][d0 + 3] = Xv.w;
        s_lxn[rr][d0 + 0] = lxn.x; s_lxn[rr][d0 + 1] = lxn.y; s_lxn[rr][d0 + 2] = lxn.z; s_lxn[rr][d0 + 3] = lxn.w;
    }
    __syncthreads();

    const bf16x8* vgxh = (const bf16x8*)gxh;
    const bf16x8* vgxl = (const bf16x8*)gxl;
    const bf16x8* vghh = (const bf16x8*)ghh;
    const bf16x8* vghl = (const bf16x8*)ghl;
    const bf16x8* vzrh = (const bf16x8*)zrh;
    const bf16x8* vzrl = (const bf16x8*)zrl;
    const bf16x8* vh3h = (const bf16x8*)h3h;
    const bf16x8* vh3l = (const bf16x8*)h3l;

    // ---- P2: gamma GEMMs. h-tiles {wave, wave+4}; x-tiles 8+wave (waves 0,1) ----
    #pragma unroll
    for (int ti = 0; ti < 2; ti++) {
        int tn = wave + ti * 4;
        bf16x8 bhi = vghh[tn * 64 + lane];
        bf16x8 blo = vghl[tn * 64 + lane];
        int c = tn * 16 + lo4;
        #pragma unroll
        for (int si = 0; si < 2; si++) {
            int ar = si * 16 + lo4;
            bf16x8 ahi = *(const bf16x8*)&sh_iv_hi[ar][hi2 * 8];
            bf16x8 alo = *(const bf16x8*)&sh_iv_lo[ar][hi2 * 8];
            f32x4 acc = {0.f, 0.f, 0.f, 0.f};
            acc = __builtin_amdgcn_mfma_f32_16x16x32_bf16(ahi, bhi, acc, 0, 0, 0);
            acc = __builtin_amdgcn_mfma_f32_16x16x32_bf16(ahi, blo, acc, 0, 0, 0);
            acc = __builtin_amdgcn_mfma_f32_16x16x32_bf16(alo, bhi, acc, 0, 0, 0);
            #pragma unroll
            for (int q = 0; q < 4; q++) {
                int r = si * 16 + hi2 * 4 + q;
                float g = __expf(-fmaxf(acc[q], 0.f));
                float hv = g * hreg[ti][si][q];
                hreg[ti][si][q] = hv;
                unsigned short hh = bfh(hv);
                sh_h_hi[r][c] = hh;
                sh_h_lo[r][c] = bfh(hv - bfh2f(hh));
            }
        }
    }
    if (wave < 2) {
        bf16x8 bhi = vgxh[wave * 64 + lane];
        bf16x8 blo = vgxl[wave * 64 + lane];
        int c = wave * 16 + lo4;
        float mn = s_mean[c];
        #pragma unroll
        for (int si = 0; si < 2; si++) {
            int ar = si * 16 + lo4;
            bf16x8 ahi = *(const bf16x8*)&sh_iv_hi[ar][hi2 * 8];
            bf16x8 alo = *(const bf16x8*)&sh_iv_lo[ar][hi2 * 8];
            f32x4 acc = {0.f, 0.f, 0.f, 0.f};
            acc = __builtin_amdgcn_mfma_f32_16x16x32_bf16(ahi, bhi, acc, 0, 0, 0);
            acc = __builtin_amdgcn_mfma_f32_16x16x32_bf16(ahi, blo, acc, 0, 0, 0);
            acc = __builtin_amdgcn_mfma_f32_16x16x32_bf16(alo, bhi, acc, 0, 0, 0);
            #pragma unroll
            for (int q = 0; q < 4; q++) {
                int r = si * 16 + hi2 * 4 + q;
                float g = __expf(-fmaxf(acc[q], 0.f));
                float Mv = bfh2f(sh_M[r][c]);
                float xh = Mv * s_X[r][c]
                         + (1.f - Mv) * (g * s_lxn[r][c] + (1.f - g) * mn);
                unsigned short xhh = bfh(xh);
                sh_xh_hi[r][c] = xhh;
                sh_xh_lo[r][c] = bfh(xh - bfh2f(xhh));
            }
        }
    }
    __syncthreads();

    // ---- P3: z/r GEMM. z tiles {wave, wave+4}; r tiles {wave+8, wave+12}; K = 192 ----
    f32x4 accA[4][2];
    #pragma unroll
    for (int ti = 0; ti < 4; ti++)
        #pragma unroll
        for (int si = 0; si < 2; si++)
            accA[ti][si] = (f32x4){0.f, 0.f, 0.f, 0.f};

    #pragma unroll
    for (int ks = 0; ks < 6; ks++) {
        bf16x8 Ah[2], Al[2];
        bool hasLo = (ks != 1);
        #pragma unroll
        for (int si = 0; si < 2; si++) {
            int ar = si * 16 + lo4;
            if (ks == 0) {
                Ah[si] = *(const bf16x8*)&sh_xh_hi[ar][hi2 * 8];
                Al[si] = *(const bf16x8*)&sh_xh_lo[ar][hi2 * 8];
            } else if (ks == 1) {
                Ah[si] = *(const bf16x8*)&sh_M[ar][hi2 * 8];
                Al[si] = Ah[si];
            } else {
                int ko = (ks - 2) * 32 + hi2 * 8;
                Ah[si] = *(const bf16x8*)&sh_h_hi[ar][ko];
                Al[si] = *(const bf16x8*)&sh_h_lo[ar][ko];
            }
        }
        #pragma unroll
        for (int ti = 0; ti < 4; ti++) {
            int tn = wave + ti * 4;
            int slot = (tn * 6 + ks) * 64 + lane;
            bf16x8 bhi = vzrh[slot];
            bf16x8 blo = vzrl[slot];
            #pragma unroll
            for (int si = 0; si < 2; si++) {
                f32x4 a = accA[ti][si];
                a = __builtin_amdgcn_mfma_f32_16x16x32_bf16(Ah[si], bhi, a, 0, 0, 0);
                a = __builtin_amdgcn_mfma_f32_16x16x32_bf16(Ah[si], blo, a, 0, 0, 0);
                if (hasLo)
                    a = __builtin_amdgcn_mfma_f32_16x16x32_bf16(Al[si], bhi, a, 0, 0, 0);
                accA[ti][si] = a;
            }
        }
    }
    // activations -> registers
    float zreg[2][2][4], rreg[2][2][4];
    #pragma unroll
    for (int ti = 0; ti < 2; ti++) {
        int c = (wave + ti * 4) * 16 + lo4;
        float bzv = bz[c];
        #pragma unroll
        for (int si = 0; si < 2; si++)
            #pragma unroll
            for (int q = 0; q < 4; q++)
                zreg[ti][si][q] = fsig(accA[ti][si][q] + bzv);
    }
    #pragma unroll
    for (int ti = 2; ti < 4; ti++) {
        int c = (wave + (ti - 2) * 4) * 16 + lo4;
        float brv = br[c];
        #pragma unroll
        for (int si = 0; si < 2; si++)
            #pragma unroll
            for (int q = 0; q < 4; q++)
                rreg[ti - 2][si][q] = fsig(accA[ti][si][q] + brv);
    }
    __syncthreads();   // all P3 reads of sh_h done

    // overwrite h planes with r*h
    #pragma unroll
    for (int tj = 0; tj < 2; tj++) {
        int c = (wave + tj * 4) * 16 + lo4;
        #pragma unroll
        for (int si = 0; si < 2; si++) {
            #pragma unroll
            for (int q = 0; q < 4; q++) {
                int r = si * 16 + hi2 * 4 + q;
                float rh = rreg[tj][si][q] * hreg[tj][si][q];
                unsigned short rhh = bfh(rh);
                sh_h_hi[r][c] = rhh;
                sh_h_lo[r][c] = bfh(rh - bfh2f(rhh));
            }
        }
    }
    __syncthreads();

    // ---- P4: h_tilde GEMM (tiles {wave, wave+4}) + output ----
    f32x4 accB[2][2];
    #pragma unroll
    for (int ti = 0; ti < 2; ti++)
        #pragma unroll
        for (int si = 0; si < 2; si++)
            accB[ti][si] = (f32x4){0.f, 0.f, 0.f, 0.f};

    #pragma unroll
    for (int ks = 0; ks < 6; ks++) {
        bf16x8 Ah[2], Al[2];
        bool hasLo = (ks != 1);
        #pragma unroll
        for (int si = 0; si < 2; si++) {
            int ar = si * 16 + lo4;
            if (ks == 0) {
                Ah[si] = *(const bf16x8*)&sh_xh_hi[ar][hi2 * 8];
                Al[si] = *(const bf16x8*)&sh_xh_lo[ar][hi2 * 8];
            } else if (ks == 1) {
                Ah[si] = *(const bf16x8*)&sh_M[ar][hi2 * 8];
                Al[si] = Ah[si];
            } else {
                int ko = (ks - 2) * 32 + hi2 * 8;
                Ah[si] = *(const bf16x8*)&sh_h_hi[ar][ko];
                Al[si] = *(const bf16x8*)&sh_h_lo[ar][ko];
            }
        }
        #pragma unroll
        for (int ti = 0; ti < 2; ti++) {
            int tn = wave + ti * 4;
            int slot = (tn * 6 + ks) * 64 + lane;
            bf16x8 bhi = vh3h[slot];
            bf16x8 blo = vh3l[slot];
            #pragma unroll
            for (int si = 0; si < 2; si++) {
                f32x4 a = accB[ti][si];
                a = __builtin_amdgcn_mfma_f32_16x16x32_bf16(Ah[si], bhi, a, 0, 0, 0);
                a = __builtin_amdgcn_mfma_f32_16x16x32_bf16(Ah[si], blo, a, 0, 0, 0);
                if (hasLo)
                    a = __builtin_amdgcn_mfma_f32_16x16x32_bf16(Al[si], bhi, a, 0, 0, 0);
                accB[ti][si] = a;
            }
        }
    }
    #pragma unroll
    for (int ti = 0; ti < 2; ti++) {
        int c = (wave + ti * 4) * 16 + lo4;
        float bhv = bh[c];
        #pragma unroll
        for (int si = 0; si < 2; si++) {
            #pragma unroll
            for (int q = 0; q < 4; q++) {
                int r = si * 16 + hi2 * 4 + q;
                int gi = s_idx[r];
                if (gi < 0) continue;
                float ht = ftanh(accB[ti][si][q] + bhv);
                float z  = zreg[ti][si][q];
                out_h[(long)gi * HID_ + c] = (1.f - z) * hreg[ti][si][q] + z * ht;
            }
        }
    }
}

extern "C" void kernel_launch(void* const* d_in, const int* in_sizes, int n_in,
                              void* d_out, int out_size, void* d_ws, size_t ws_size,
                              hipStream_t stream)
{
    const float* ct     = (const float*)d_in[0];
    const float* mgn_h  = (const float*)d_in[1];
    const float* X_obs  = (const float*)d_in[2];
    const float* M_obs  = (const float*)d_in[3];
    const int*   i_obs  = (const int*)d_in[4];
    const float* last_x = (const float*)d_in[5];
    const float* last_t = (const float*)d_in[6];
    const float* W_gx   = (const float*)d_in[7];
    const float* W_gh   = (const float*)d_in[8];
    const float* Wz = (const float*)d_in[9];
    const float* Vz = (const float*)d_in[10];
    const float* Uz = (const float*)d_in[11];
    const float* bz = (const float*)d_in[12];
    const float* Wr = (const float*)d_in[13];
    const float* Vr = (const float*)d_in[14];
    const float* Ur = (const float*)d_in[15];
    const float* br = (const float*)d_in[16];
    const float* Wh = (const float*)d_in[17];
    const float* Vh = (const float*)d_in[18];
    const float* Uh = (const float*)d_in[19];
    const float* bh = (const float*)d_in[20];

    int n_obs = in_sizes[4];
    int N = in_sizes[1] / HID_;

    float* out_h  = (float*)d_out;
    float* out_lx = out_h + (long)N * HID_;
    float* out_lt = out_lx + (long)N * D_;

    char* w = (char*)d_ws;
    float* partials = (float*)w;                       // 32768 B
    float* mean_x   = (float*)(w + 32768);             // 128 B
    short* gxh = (short*)(w + 32896);                  // 2048 B
    short* gxl = (short*)(w + 32896 + 2048);
    short* ghh = (short*)(w + 36992);                  // 8192 B
    short* ghl = (short*)(w + 36992 + 8192);
    short* zrh = (short*)(w + 53376);                  // 98304 B
    short* zrl = (short*)(w + 53376 + 98304);
    short* h3h = (short*)(w + 249984);                 // 49152 B
    short* h3l = (short*)(w + 249984 + 49152);
    unsigned* bm = (unsigned*)(w + 348288);            // 25000 B bitmap

    int nwords = (N + 31) / 32;
    hipMemsetAsync(bm, 0, (size_t)nwords * 4, stream);
    k_bitset<<<(n_obs + 255) / 256, 256, 0, stream>>>(i_obs, bm, n_obs);
    k_prep<<<308, 256, 0, stream>>>(W_gx, W_gh, Wz, Vz, Uz, Wr, Vr, Ur, Wh, Vh, Uh,
                                    gxh, gxl, ghh, ghl, zrh, zrl, h3h, h3l);
    int chunk = (n_obs + 127) / 128;
    k_mean1<<<128, 256, 0, stream>>>(X_obs, M_obs, partials, n_obs, chunk);
    k_mean2<<<1, 64, 0, stream>>>(partials, mean_x, 128);
    k_copy<<<2048, 256, 0, stream>>>((const float4*)mgn_h, (const float4*)last_x, (const float4*)last_t,
                                     (float4*)out_h, (float4*)out_lx, (float4*)out_lt, bm, N);
    int nblk = (n_obs + ROWS - 1) / ROWS;
    k_main<<<nblk, 256, 0, stream>>>(ct, mgn_h, X_obs, M_obs, i_obs, last_x, last_t,
                                     bz, br, bh, mean_x,
                                     gxh, gxl, ghh, ghl, zrh, zrl, h3h, h3l,
                                     out_h, out_lx, out_lt, n_obs);
}